// Round 2
// baseline (48.962 us; speedup 1.0000x reference)
//
#include <hip/hip_runtime.h>
#include <math.h>

#define TEMP_INV 20.0f
#define EPS_F 1e-6f

// Kernel 1: per-row cosine sim vs anchor, exp(), per-block partial sums.
// One wave per row-pair iteration; each wave owns a contiguous chunk of rows.
__global__ __launch_bounds__(256) void infonce_neg_pass(
    const float* __restrict__ a,
    const float* __restrict__ neg,
    float* __restrict__ partials,
    int N)
{
    __shared__ float a_lds[1024];
    __shared__ float red[256];

    const int tid = threadIdx.x;

    // Stage anchor into LDS and compute ||a||^2 cooperatively (per block).
    float4 av = ((const float4*)a)[tid];
    ((float4*)a_lds)[tid] = av;
    red[tid] = av.x * av.x + av.y * av.y + av.z * av.z + av.w * av.w;
    __syncthreads();
    for (int s = 128; s > 0; s >>= 1) {
        if (tid < s) red[tid] += red[tid + s];
        __syncthreads();
    }
    const float anorm = sqrtf(red[0]);
    __syncthreads();  // red reused below

    const int lane = tid & 63;
    const int wave = tid >> 6;

    // Lane's anchor fragment, interleaved: float4 index j*64 + lane.
    float4 areg[4];
    #pragma unroll
    for (int j = 0; j < 4; ++j)
        areg[j] = ((const float4*)a_lds)[j * 64 + lane];

    const int gwave = blockIdx.x * 4 + wave;
    const int total_waves = gridDim.x * 4;
    const int chunk = (N + total_waves - 1) / total_waves;
    const int base = gwave * chunk;
    const int end = (base + chunk < N) ? base + chunk : N;

    float local = 0.0f;
    for (int row = base; row < end; row += 2) {
        const bool two = (row + 1 < end);  // wave-uniform
        const float4* r0 = (const float4*)neg + (size_t)row * 256;
        const float4* r1 = r0 + 256;

        // Issue all 8 loads (128 B/lane in flight) before any use.
        float4 v0[4], v1[4];
        #pragma unroll
        for (int j = 0; j < 4; ++j) v0[j] = r0[j * 64 + lane];
        if (two) {
            #pragma unroll
            for (int j = 0; j < 4; ++j) v1[j] = r1[j * 64 + lane];
        }

        float d0 = 0.f, n0 = 0.f, d1 = 0.f, n1 = 0.f;
        #pragma unroll
        for (int j = 0; j < 4; ++j) {
            d0 += v0[j].x * areg[j].x + v0[j].y * areg[j].y
                + v0[j].z * areg[j].z + v0[j].w * areg[j].w;
            n0 += v0[j].x * v0[j].x + v0[j].y * v0[j].y
                + v0[j].z * v0[j].z + v0[j].w * v0[j].w;
        }
        if (two) {
            #pragma unroll
            for (int j = 0; j < 4; ++j) {
                d1 += v1[j].x * areg[j].x + v1[j].y * areg[j].y
                    + v1[j].z * areg[j].z + v1[j].w * areg[j].w;
                n1 += v1[j].x * v1[j].x + v1[j].y * v1[j].y
                    + v1[j].z * v1[j].z + v1[j].w * v1[j].w;
            }
        }

        // Two interleaved 64-lane butterflies — chains overlap, latency halves.
        #pragma unroll
        for (int off = 32; off > 0; off >>= 1) {
            d0 += __shfl_xor(d0, off);
            n0 += __shfl_xor(n0, off);
            d1 += __shfl_xor(d1, off);
            n1 += __shfl_xor(n1, off);
        }

        const float s0 = d0 / fmaxf(anorm * sqrtf(n0), EPS_F) * TEMP_INV;
        local += expf(s0);
        if (two) {
            const float s1 = d1 / fmaxf(anorm * sqrtf(n1), EPS_F) * TEMP_INV;
            local += expf(s1);
        }
    }

    if (lane == 0) red[wave] = local;
    __syncthreads();
    if (tid == 0)
        partials[blockIdx.x] = red[0] + red[1] + red[2] + red[3];
}

// Kernel 2: single block. Reduce block partials, compute pos_sim, final loss.
__global__ __launch_bounds__(256) void infonce_finalize(
    const float* __restrict__ a,
    const float* __restrict__ p,
    const float* __restrict__ partials,
    int nparts,
    float* __restrict__ out)
{
    __shared__ float r0[256], r1[256], r2[256], r3[256];
    const int tid = threadIdx.x;

    float4 av = ((const float4*)a)[tid];
    float4 pv = ((const float4*)p)[tid];
    r0[tid] = av.x * pv.x + av.y * pv.y + av.z * pv.z + av.w * pv.w;
    r1[tid] = av.x * av.x + av.y * av.y + av.z * av.z + av.w * av.w;
    r2[tid] = pv.x * pv.x + pv.y * pv.y + pv.z * pv.z + pv.w * pv.w;

    float nloc = 0.0f;
    for (int i = tid; i < nparts; i += 256) nloc += partials[i];
    r3[tid] = nloc;
    __syncthreads();

    for (int s = 128; s > 0; s >>= 1) {
        if (tid < s) {
            r0[tid] += r0[tid + s];
            r1[tid] += r1[tid + s];
            r2[tid] += r2[tid + s];
            r3[tid] += r3[tid + s];
        }
        __syncthreads();
    }

    if (tid == 0) {
        const float pos_sim =
            r0[0] / fmaxf(sqrtf(r1[0]) * sqrtf(r2[0]), EPS_F) * TEMP_INV;
        out[0] = -logf(expf(pos_sim) / r3[0] + EPS_F);
    }
}

extern "C" void kernel_launch(void* const* d_in, const int* in_sizes, int n_in,
                              void* d_out, int out_size, void* d_ws, size_t ws_size,
                              hipStream_t stream) {
    const float* a   = (const float*)d_in[0];
    const float* p   = (const float*)d_in[1];
    const float* neg = (const float*)d_in[2];
    const int D = in_sizes[0];            // 1024 for this problem
    const int N = in_sizes[2] / D;        // 65536
    float* out      = (float*)d_out;
    float* partials = (float*)d_ws;       // nblocks floats

    int nblocks = 2048;                   // 8 blocks/CU, 32 waves/CU resident
    if (nblocks * 4 > N) nblocks = (N + 3) / 4;

    infonce_neg_pass<<<nblocks, 256, 0, stream>>>(a, neg, partials, N);
    infonce_finalize<<<1, 256, 0, stream>>>(a, p, partials, nblocks, out);
}